// Round 4
// baseline (250.095 us; speedup 1.0000x reference)
//
#include <hip/hip_runtime.h>
#include <hip/hip_fp16.h>
#include <math.h>

#define C_DIM 256
#define H_DIM 8
#define L_DIM 4
#define P_DIM 4
#define LQ 5440
#define LEN_IN 5440
#define NB 4
#define M_ROWS (NB * LQ)   // 21760

typedef __attribute__((ext_vector_type(8))) _Float16 f16x8;
typedef __attribute__((ext_vector_type(4))) float f32x4;

__device__ __forceinline__ void split_f32(float a, __half& h, __half& l) {
    h = __float2half(a);
    l = __float2half(a - __half2float(h));
}

// ---- activation split: fp32 [M,256] -> hi/lo f16 [M,256] (memory-bound pass) ----
__global__ __launch_bounds__(256) void convert_act(const float* __restrict__ in,
                                                   __half* __restrict__ hi,
                                                   __half* __restrict__ lo) {
    const int i = blockIdx.x * 256 + threadIdx.x;   // one float4 per thread
    const float4 v = ((const float4*)in)[i];
    __half h0, h1, h2, h3, l0, l1, l2, l3;
    split_f32(v.x, h0, l0); split_f32(v.y, h1, l1);
    split_f32(v.z, h2, l2); split_f32(v.w, h3, l3);
    ushort4 uh, ul;
    uh.x = __half_as_ushort(h0); uh.y = __half_as_ushort(h1);
    uh.z = __half_as_ushort(h2); uh.w = __half_as_ushort(h3);
    ul.x = __half_as_ushort(l0); ul.y = __half_as_ushort(l1);
    ul.z = __half_as_ushort(l2); ul.w = __half_as_ushort(l3);
    ((ushort4*)hi)[i] = uh;
    ((ushort4*)lo)[i] = ul;
}

// ---- weight split + transpose: fp32 [256,ncols] -> hi/lo f16 [ncols,256] ----
__global__ __launch_bounds__(256) void convert_wt(const float* __restrict__ w,
                                                  __half* __restrict__ hi,
                                                  __half* __restrict__ lo, int ncols) {
    const int ncol = blockIdx.x;     // output row
    const int k = threadIdx.x;       // output col (coalesced writes)
    const float a = w[(size_t)k * ncols + ncol];
    __half h, l;
    split_f32(a, h, l);
    hi[(size_t)ncol * 256 + k] = h;
    lo[(size_t)ncol * 256 + k] = l;
}

// ---------------- f16x3 MFMA GEMM: out[M x NC] = A[M x 256] @ W^T + bias ------------
// A given as hi/lo f16 [M][256]; W given as hi/lo f16 TRANSPOSED [NC][256].
// BM=64, BN=128, BK=32, 256 threads = 2x2 waves, each wave owns 32x64 (2x4 frags of
// 16x16x32). fp32 emulated as Ahi*Bhi + Alo*Bhi + Ahi*Blo (3 MFMA).
// 680 blocks for NC=256 (2.7/CU) + launch_bounds(256,3): latency hidden by TLP.
// LDS [comp][row][32] halfs with XOR chunk swizzle ch^((row>>1)&3).
template <int NC>
__global__ __launch_bounds__(256, 3) void gemm_f16x3(const __half* __restrict__ Ahi,
                                                     const __half* __restrict__ Alo,
                                                     const __half* __restrict__ Bhi,
                                                     const __half* __restrict__ Blo,
                                                     const float* __restrict__ bias,
                                                     float* __restrict__ outp) {
    __shared__ __align__(16) __half sA[2][64][32];
    __shared__ __align__(16) __half sB[2][128][32];

    const int n0 = blockIdx.x * 128;
    const int row0 = blockIdx.y * 64;
    const int t = threadIdx.x;
    const int w = t >> 6, lane = t & 63;
    const int bm = (w >> 1) * 32, bn = (w & 1) * 64;
    const int fr = lane & 15;   // frag row (A) / col (B) / col (C)
    const int fc = lane >> 4;   // frag k-chunk (0..3); C row group

    // A staging: 256 float4 per comp; B staging: 512 float4 per comp (2 per thread)
    const int ar = t >> 2, ac = t & 3;
    const int asw = (ac ^ ((ar >> 1) & 3)) * 8;
    const int br1 = t >> 2, br2 = br1 + 64;
    const int bsw1 = (ac ^ ((br1 >> 1) & 3)) * 8;
    const int bsw2 = (ac ^ ((br2 >> 1) & 3)) * 8;

    const size_t ga  = (size_t)(row0 + ar) * 256 + ac * 8;
    const size_t gb1 = (size_t)(n0 + br1) * 256 + ac * 8;
    const size_t gb2 = (size_t)(n0 + br2) * 256 + ac * 8;

    f32x4 acc[2][4];
#pragma unroll
    for (int m = 0; m < 2; ++m)
#pragma unroll
        for (int n = 0; n < 4; ++n)
#pragma unroll
            for (int r = 0; r < 4; ++r) acc[m][n][r] = 0.f;

    float4 pf[6];
    pf[0] = *(const float4*)(Ahi + ga);
    pf[1] = *(const float4*)(Alo + ga);
    pf[2] = *(const float4*)(Bhi + gb1);
    pf[3] = *(const float4*)(Bhi + gb2);
    pf[4] = *(const float4*)(Blo + gb1);
    pf[5] = *(const float4*)(Blo + gb2);

    for (int kt = 0; kt < 8; ++kt) {
        if (kt) __syncthreads();
        *(float4*)&sA[0][ar][asw] = pf[0];
        *(float4*)&sA[1][ar][asw] = pf[1];
        *(float4*)&sB[0][br1][bsw1] = pf[2];
        *(float4*)&sB[0][br2][bsw2] = pf[3];
        *(float4*)&sB[1][br1][bsw1] = pf[4];
        *(float4*)&sB[1][br2][bsw2] = pf[5];
        __syncthreads();
        if (kt < 7) {
            const size_t ko = (size_t)(kt + 1) * 32;
            pf[0] = *(const float4*)(Ahi + ga + ko);
            pf[1] = *(const float4*)(Alo + ga + ko);
            pf[2] = *(const float4*)(Bhi + gb1 + ko);
            pf[3] = *(const float4*)(Bhi + gb2 + ko);
            pf[4] = *(const float4*)(Blo + gb1 + ko);
            pf[5] = *(const float4*)(Blo + gb2 + ko);
        }

        f16x8 bhf[4], blf[4];
#pragma unroll
        for (int n = 0; n < 4; ++n) {
            const int rowb = bn + n * 16 + fr;
            const int swb = (fc ^ ((rowb >> 1) & 3)) * 8;
            bhf[n] = *(const f16x8*)&sB[0][rowb][swb];
            blf[n] = *(const f16x8*)&sB[1][rowb][swb];
        }
#pragma unroll
        for (int m = 0; m < 2; ++m) {
            const int rowa = bm + m * 16 + fr;
            const int swa = (fc ^ ((rowa >> 1) & 3)) * 8;
            const f16x8 ah = *(const f16x8*)&sA[0][rowa][swa];
            const f16x8 al = *(const f16x8*)&sA[1][rowa][swa];
#pragma unroll
            for (int n = 0; n < 4; ++n) {
                acc[m][n] = __builtin_amdgcn_mfma_f32_16x16x32_f16(ah, bhf[n], acc[m][n], 0, 0, 0);
                acc[m][n] = __builtin_amdgcn_mfma_f32_16x16x32_f16(al, bhf[n], acc[m][n], 0, 0, 0);
                acc[m][n] = __builtin_amdgcn_mfma_f32_16x16x32_f16(ah, blf[n], acc[m][n], 0, 0, 0);
            }
        }
    }

    // epilogue: C/D layout col = lane&15, row = (lane>>4)*4 + reg
#pragma unroll
    for (int n = 0; n < 4; ++n) {
        const int col = n0 + bn + n * 16 + fr;
        const float bv = bias[col];
#pragma unroll
        for (int m = 0; m < 2; ++m) {
            const int row = row0 + bm + m * 16 + fc * 4;
#pragma unroll
            for (int r = 0; r < 4; ++r)
                outp[(size_t)(row + r) * NC + col] = acc[m][n][r] + bv;
        }
    }
}

// ---------------- Sampling: softmax + bilinear gather + weighted sum ----------------
// 256 threads = 4 waves, one QUERY PER WAVE (raises the 16-workgroup/CU occupancy cap
// from 16 to 32 waves/CU). LDS slot permutation p = lp*8 + (h^(lp&7)): bijective;
// reads (fixed lp, 8 h-groups) hit 8 distinct bank-quads, writes (fixed h, 16 lp)
// spread 2 lanes/quad = free. Writes result as hi/lo f16 for the final f16x3 GEMM.
__global__ __launch_bounds__(256) void sample_kernel(const float* __restrict__ value,   // [N*LEN_IN, C]
                                                     const float* __restrict__ offv,    // [N*LQ, 256]
                                                     const float* __restrict__ logits,  // [N*LQ, 128]
                                                     const float* __restrict__ refpts,  // [N, LQ, L, 2]
                                                     __half* __restrict__ tmp_hi,       // [N*LQ, C]
                                                     __half* __restrict__ tmp_lo) {
    const int t = threadIdx.x;
    const int w = t >> 6, lane = t & 63;
    const int q = blockIdx.x * 4 + w;
    const int n = q / LQ;

    __shared__ __align__(16) float4 s_aw[4][128];
    __shared__ __align__(16) int4 s_of[4][128];

#pragma unroll
    for (int s = 0; s < 2; ++s) {
        const int j = lane + 64 * s;     // slot = h*16 + lp, lp = (l<<2)|p
        const int h = j >> 4, lp = j & 15;
        const int l = lp >> 2;
        const int ww = 64 >> l;
        int st = 0;
        if (l == 1) st = 4096;
        else if (l == 2) st = 5120;
        else if (l == 3) st = 5376;

        const float2 oxy = *(const float2*)&offv[(size_t)q * 256 + 2 * j];
        const float2 rxy = *(const float2*)&refpts[((size_t)q * L_DIM + l) * 2];

        const float fw = (float)ww;
        const float x = fminf(fmaxf(rxy.x + oxy.x, 0.f), 1.f) * fw - 0.5f;
        const float y = fminf(fmaxf(rxy.y + oxy.y, 0.f), 1.f) * fw - 0.5f;
        const int xi = (int)floorf(x);
        const int yi = (int)floorf(y);
        const int x0i = min(max(xi, 0), ww - 1);
        const int x1i = min(max(xi + 1, 0), ww - 1);
        const int y0i = min(max(yi, 0), ww - 1);
        const int y1i = min(max(yi + 1, 0), ww - 1);
        const float wx0 = (float)x1i - x, wx1 = x - (float)x0i;
        const float wy0 = (float)y1i - y, wy1 = y - (float)y0i;

        // softmax over the 16 (l,p) slots of this head (16-lane aligned groups)
        const float lg = logits[(size_t)q * 128 + j];
        float m = lg;
#pragma unroll
        for (int o = 8; o; o >>= 1) m = fmaxf(m, __shfl_xor(m, o, 16));
        const float e = expf(lg - m);
        float sm = e;
#pragma unroll
        for (int o = 8; o; o >>= 1) sm += __shfl_xor(sm, o, 16);
        const float a = e / sm;

        const int p = lp * 8 + (h ^ (lp & 7));   // bijective bank-spread permutation
        float4 aw;
        aw.x = a * (wx0 * wy0);   // (y0,x0)
        aw.y = a * (wx0 * wy1);   // (y1,x0)
        aw.z = a * (wx1 * wy0);   // (y0,x1)
        aw.w = a * (wx1 * wy1);   // (y1,x1)
        int4 of;
        of.x = (st + y0i * ww + x0i) << 10;      // row byte offset (256 floats)
        of.y = (st + y1i * ww + x0i) << 10;
        of.z = (st + y0i * ww + x1i) << 10;
        of.w = (st + y1i * ww + x1i) << 10;
        s_aw[w][p] = aw;
        s_of[w][p] = of;
    }
    __syncthreads();

    const int h = lane >> 3;
    const char* vb = (const char*)value + (size_t)n * LEN_IN * C_DIM * 4 + (size_t)(lane * 16);
    float4 acc;
    acc.x = 0.f; acc.y = 0.f; acc.z = 0.f; acc.w = 0.f;
#pragma unroll
    for (int lp = 0; lp < 16; ++lp) {
        const int p = lp * 8 + (h ^ (lp & 7));
        const float4 aw = s_aw[w][p];
        const int4 of = s_of[w][p];
        const float4 v0 = *(const float4*)(vb + of.x);
        const float4 v1 = *(const float4*)(vb + of.y);
        const float4 v2 = *(const float4*)(vb + of.z);
        const float4 v3 = *(const float4*)(vb + of.w);
        acc.x += aw.x * v0.x + aw.y * v1.x + aw.z * v2.x + aw.w * v3.x;
        acc.y += aw.x * v0.y + aw.y * v1.y + aw.z * v2.y + aw.w * v3.y;
        acc.z += aw.x * v0.z + aw.y * v1.z + aw.z * v2.z + aw.w * v3.z;
        acc.w += aw.x * v0.w + aw.y * v1.w + aw.z * v2.w + aw.w * v3.w;
    }

    __half h0, h1, h2, h3, l0, l1, l2, l3;
    split_f32(acc.x, h0, l0); split_f32(acc.y, h1, l1);
    split_f32(acc.z, h2, l2); split_f32(acc.w, h3, l3);
    ushort4 uh, ul;
    uh.x = __half_as_ushort(h0); uh.y = __half_as_ushort(h1);
    uh.z = __half_as_ushort(h2); uh.w = __half_as_ushort(h3);
    ul.x = __half_as_ushort(l0); ul.y = __half_as_ushort(l1);
    ul.z = __half_as_ushort(l2); ul.w = __half_as_ushort(l3);
    const size_t base = (size_t)q * 256 + (size_t)(lane * 4);
    *(ushort4*)&tmp_hi[base] = uh;
    *(ushort4*)&tmp_lo[base] = ul;
}

extern "C" void kernel_launch(void* const* d_in, const int* in_sizes, int n_in,
                              void* d_out, int out_size, void* d_ws, size_t ws_size,
                              hipStream_t stream) {
    const float* query         = (const float*)d_in[0];
    const float* refpts        = (const float*)d_in[1];
    const float* input_flatten = (const float*)d_in[2];
    // d_in[3] = input_spatial_shapes, d_in[4] = input_level_start_index (static, hardcoded)
    const float* w_off  = (const float*)d_in[5];
    const float* b_off  = (const float*)d_in[6];
    const float* w_attn = (const float*)d_in[7];
    const float* b_attn = (const float*)d_in[8];
    const float* w_val  = (const float*)d_in[9];
    const float* b_val  = (const float*)d_in[10];
    const float* w_out  = (const float*)d_in[11];
    const float* b_out  = (const float*)d_in[12];
    float* out = (float*)d_out;

    const size_t nr = (size_t)M_ROWS;           // 21760
    float* ws = (float*)d_ws;
    float* value_ws = ws;                        // fp32 [M,256]
    float* offv_ws  = value_ws + nr * 256;       // fp32 [M,256]
    float* logit_ws = offv_ws + nr * 256;        // fp32 [M,128]
    __half* q_hi = (__half*)(logit_ws + nr * 128);  // f16 [M,256] (reused as tmp_hi)
    __half* q_lo = q_hi + nr * 256;                 // f16 [M,256] (reused as tmp_lo)
    __half* wv_hi = q_lo + nr * 256;             // weights hi/lo, transposed [NC][256]
    __half* wv_lo = wv_hi + 256 * 256;
    __half* wo_hi = wv_lo + 256 * 256;
    __half* wo_lo = wo_hi + 256 * 256;
    __half* wa_hi = wo_lo + 256 * 256;
    __half* wa_lo = wa_hi + 128 * 256;
    __half* wt_hi = wa_lo + 128 * 256;
    __half* wt_lo = wt_hi + 256 * 256;
    // input_flatten halves live in d_out (scratch until the final GEMM overwrites it)
    __half* if_hi = (__half*)d_out;
    __half* if_lo = if_hi + nr * 256;

    const int NV4 = (int)(nr * 256 / 4);         // float4 count per activation

    convert_act<<<NV4 / 256, 256, 0, stream>>>(input_flatten, if_hi, if_lo);
    convert_act<<<NV4 / 256, 256, 0, stream>>>(query, q_hi, q_lo);
    convert_wt<<<256, 256, 0, stream>>>(w_val, wv_hi, wv_lo, 256);
    convert_wt<<<256, 256, 0, stream>>>(w_off, wo_hi, wo_lo, 256);
    convert_wt<<<128, 256, 0, stream>>>(w_attn, wa_hi, wa_lo, 128);
    convert_wt<<<256, 256, 0, stream>>>(w_out, wt_hi, wt_lo, 256);

    dim3 g256(2, M_ROWS / 64);    // (2, 340) = 680 blocks
    dim3 g128(1, M_ROWS / 64);    // (1, 340)

    gemm_f16x3<256><<<g256, 256, 0, stream>>>(if_hi, if_lo, wv_hi, wv_lo, b_val, value_ws);
    gemm_f16x3<256><<<g256, 256, 0, stream>>>(q_hi, q_lo, wo_hi, wo_lo, b_off, offv_ws);
    gemm_f16x3<128><<<g128, 256, 0, stream>>>(q_hi, q_lo, wa_hi, wa_lo, b_attn, logit_ws);

    // sample overwrites q_hi/q_lo with tmp hi/lo (q no longer needed)
    sample_kernel<<<M_ROWS / 4, 256, 0, stream>>>(value_ws, offv_ws, logit_ws, refpts, q_hi, q_lo);

    gemm_f16x3<256><<<g256, 256, 0, stream>>>(q_hi, q_lo, wt_hi, wt_lo, b_out, out);
}

// Round 5
// 154.757 us; speedup vs baseline: 1.6161x; 1.6161x over previous
//
#include <hip/hip_runtime.h>
#include <hip/hip_fp16.h>
#include <math.h>

#define C_DIM 256
#define H_DIM 8
#define L_DIM 4
#define P_DIM 4
#define LQ 5440
#define LEN_IN 5440
#define NB 4
#define M_ROWS (NB * LQ)   // 21760

typedef __attribute__((ext_vector_type(8))) _Float16 f16x8;
typedef __attribute__((ext_vector_type(8))) unsigned short u16x8;
typedef __attribute__((ext_vector_type(4))) float f32x4;

__device__ __forceinline__ void split_f32(float a, __half& h, __half& l) {
    h = __float2half(a);
    l = __float2half(a - __half2float(h));
}

// ---- weight split + transpose: fp32 [256,ncols] -> hi/lo f16 [ncols,256] ----
__global__ __launch_bounds__(256) void convert_wt(const float* __restrict__ w,
                                                  __half* __restrict__ hi,
                                                  __half* __restrict__ lo, int ncols) {
    const int ncol = blockIdx.x;     // output row
    const int k = threadIdx.x;       // output col (coalesced writes)
    const float a = w[(size_t)k * ncols + ncol];
    __half h, l;
    split_f32(a, h, l);
    hi[(size_t)ncol * 256 + k] = h;
    lo[(size_t)ncol * 256 + k] = l;
}

// ---------------- f16x3 MFMA GEMM: out[M x NC] = A[M x 256] @ W^T + bias ------------
// A is fp32 [M][256]; hi/lo split happens INLINE during LDS staging (v_cvt).
// W pre-split hi/lo f16, TRANSPOSED [NC][256]. BM=BN=128, BK=32, 256 threads =
// 2x2 waves, each wave owns 64x64 (4x4 frags of 16x16x32).
// fp32 emulated as Ahi*Bhi + Alo*Bhi + Ahi*Blo (3 MFMA).
// LDS [comp][row][32] halfs, XOR chunk swizzle ch^((row>>1)&3) on 16B chunks.
template <int NC>
__global__ __launch_bounds__(256, 2) void gemm_f16x3(const float* __restrict__ A,
                                                     const __half* __restrict__ Bhi,
                                                     const __half* __restrict__ Blo,
                                                     const float* __restrict__ bias,
                                                     float* __restrict__ outp) {
    __shared__ __align__(16) __half sA[2][128][32];
    __shared__ __align__(16) __half sB[2][128][32];

    const int n0 = blockIdx.x * 128;
    const int row0 = blockIdx.y * 128;
    const int t = threadIdx.x;
    const int w = t >> 6, lane = t & 63;
    const int bm = (w >> 1) * 64, bn = (w & 1) * 64;
    const int fr = lane & 15;   // frag row (A) / col (B) / col (C)
    const int fc = lane >> 4;   // frag k-chunk (0..3); C row group

    // A: 512 8-float chunks per tile; thread t handles chunks t, t+256
    const int ar1 = t >> 2, ar2 = ar1 + 64;     // chunk rows
    const int ak8 = t & 3;                      // 8-float group within BK=32
    const int asw1 = (ak8 ^ ((ar1 >> 1) & 3)) * 8;
    const int asw2 = (ak8 ^ ((ar2 >> 1) & 3)) * 8;
    // B: 512 16B chunks per comp; thread t handles chunks t, t+256
    const int br1 = t >> 2, br2 = br1 + 64;
    const int bc8 = t & 3;
    const int bsw1 = (bc8 ^ ((br1 >> 1) & 3)) * 8;
    const int bsw2 = (bc8 ^ ((br2 >> 1) & 3)) * 8;

    const size_t ga1 = (size_t)(row0 + ar1) * 256 + ak8 * 8;   // fp32 floats
    const size_t ga2 = (size_t)(row0 + ar2) * 256 + ak8 * 8;
    const size_t gb1 = (size_t)(n0 + br1) * 256 + bc8 * 8;     // f16 halfs
    const size_t gb2 = (size_t)(n0 + br2) * 256 + bc8 * 8;

    f32x4 acc[4][4];
#pragma unroll
    for (int m = 0; m < 4; ++m)
#pragma unroll
        for (int n = 0; n < 4; ++n)
#pragma unroll
            for (int r = 0; r < 4; ++r) acc[m][n][r] = 0.f;

    float4 pa[4];
    float4 pb[4];
    pa[0] = *(const float4*)(A + ga1);
    pa[1] = *(const float4*)(A + ga1 + 4);
    pa[2] = *(const float4*)(A + ga2);
    pa[3] = *(const float4*)(A + ga2 + 4);
    pb[0] = *(const float4*)(Bhi + gb1);
    pb[1] = *(const float4*)(Bhi + gb2);
    pb[2] = *(const float4*)(Blo + gb1);
    pb[3] = *(const float4*)(Blo + gb2);

    for (int kt = 0; kt < 8; ++kt) {
        if (kt) __syncthreads();
        // inline split of the two A chunks
#pragma unroll
        for (int ch = 0; ch < 2; ++ch) {
            const float4 u = pa[2 * ch], v = pa[2 * ch + 1];
            const float e[8] = {u.x, u.y, u.z, u.w, v.x, v.y, v.z, v.w};
            u16x8 Hh, Ll;
#pragma unroll
            for (int i = 0; i < 8; ++i) {
                __half h, l;
                split_f32(e[i], h, l);
                Hh[i] = __half_as_ushort(h);
                Ll[i] = __half_as_ushort(l);
            }
            const int row = ch ? ar2 : ar1;
            const int sw = ch ? asw2 : asw1;
            *(u16x8*)&sA[0][row][sw] = Hh;
            *(u16x8*)&sA[1][row][sw] = Ll;
        }
        *(float4*)&sB[0][br1][bsw1] = pb[0];
        *(float4*)&sB[0][br2][bsw2] = pb[1];
        *(float4*)&sB[1][br1][bsw1] = pb[2];
        *(float4*)&sB[1][br2][bsw2] = pb[3];
        __syncthreads();
        if (kt < 7) {
            const size_t ko = (size_t)(kt + 1) * 32;
            pa[0] = *(const float4*)(A + ga1 + ko);
            pa[1] = *(const float4*)(A + ga1 + ko + 4);
            pa[2] = *(const float4*)(A + ga2 + ko);
            pa[3] = *(const float4*)(A + ga2 + ko + 4);
            pb[0] = *(const float4*)(Bhi + gb1 + ko);
            pb[1] = *(const float4*)(Bhi + gb2 + ko);
            pb[2] = *(const float4*)(Blo + gb1 + ko);
            pb[3] = *(const float4*)(Blo + gb2 + ko);
        }

        f16x8 bhf[4], blf[4];
#pragma unroll
        for (int n = 0; n < 4; ++n) {
            const int rowb = bn + n * 16 + fr;
            const int swb = (fc ^ ((rowb >> 1) & 3)) * 8;
            bhf[n] = *(const f16x8*)&sB[0][rowb][swb];
            blf[n] = *(const f16x8*)&sB[1][rowb][swb];
        }
#pragma unroll
        for (int m = 0; m < 4; ++m) {
            const int rowa = bm + m * 16 + fr;
            const int swa = (fc ^ ((rowa >> 1) & 3)) * 8;
            const f16x8 ah = *(const f16x8*)&sA[0][rowa][swa];
            const f16x8 al = *(const f16x8*)&sA[1][rowa][swa];
#pragma unroll
            for (int n = 0; n < 4; ++n) {
                acc[m][n] = __builtin_amdgcn_mfma_f32_16x16x32_f16(ah, bhf[n], acc[m][n], 0, 0, 0);
                acc[m][n] = __builtin_amdgcn_mfma_f32_16x16x32_f16(al, bhf[n], acc[m][n], 0, 0, 0);
                acc[m][n] = __builtin_amdgcn_mfma_f32_16x16x32_f16(ah, blf[n], acc[m][n], 0, 0, 0);
            }
        }
    }

    // epilogue: C/D layout col = lane&15, row = (lane>>4)*4 + reg
#pragma unroll
    for (int n = 0; n < 4; ++n) {
        const int col = n0 + bn + n * 16 + fr;
        const float bv = bias[col];
#pragma unroll
        for (int m = 0; m < 4; ++m) {
            const int row = row0 + bm + m * 16 + fc * 4;
#pragma unroll
            for (int r = 0; r < 4; ++r)
                outp[(size_t)(row + r) * NC + col] = acc[m][n][r] + bv;
        }
    }
}

// ---------------- Sampling: softmax + bilinear gather + weighted sum ----------------
// 128 threads = 2 waves, one QUERY PER WAVE. 16-workgroup/CU cap -> 32 waves/CU
// potential. LDS slot permutation p = lp*8 + (h^(lp&7)): bijective, conflict-free
// for both writers and readers. ol = fused [offv(256) | logits(128)] rows of 384.
// Output written fp32 (the final GEMM splits inline).
__global__ __launch_bounds__(128) void sample_kernel(const float* __restrict__ value,   // [N*LEN_IN, C]
                                                     const float* __restrict__ ol,      // [N*LQ, 384]
                                                     const float* __restrict__ refpts,  // [N, LQ, L, 2]
                                                     float* __restrict__ tmp) {         // [N*LQ, C]
    const int t = threadIdx.x;
    const int w = t >> 6, lane = t & 63;
    const int q = blockIdx.x * 2 + w;
    const int n = q / LQ;

    __shared__ __align__(16) float4 s_aw[2][128];
    __shared__ __align__(16) int4 s_of[2][128];

#pragma unroll
    for (int s = 0; s < 2; ++s) {
        const int j = lane + 64 * s;     // slot = h*16 + lp, lp = (l<<2)|p
        const int h = j >> 4, lp = j & 15;
        const int l = lp >> 2;
        const int ww = 64 >> l;
        int st = 0;
        if (l == 1) st = 4096;
        else if (l == 2) st = 5120;
        else if (l == 3) st = 5376;

        const float2 oxy = *(const float2*)&ol[(size_t)q * 384 + 2 * j];
        const float2 rxy = *(const float2*)&refpts[((size_t)q * L_DIM + l) * 2];

        const float fw = (float)ww;
        const float x = fminf(fmaxf(rxy.x + oxy.x, 0.f), 1.f) * fw - 0.5f;
        const float y = fminf(fmaxf(rxy.y + oxy.y, 0.f), 1.f) * fw - 0.5f;
        const int xi = (int)floorf(x);
        const int yi = (int)floorf(y);
        const int x0i = min(max(xi, 0), ww - 1);
        const int x1i = min(max(xi + 1, 0), ww - 1);
        const int y0i = min(max(yi, 0), ww - 1);
        const int y1i = min(max(yi + 1, 0), ww - 1);
        const float wx0 = (float)x1i - x, wx1 = x - (float)x0i;
        const float wy0 = (float)y1i - y, wy1 = y - (float)y0i;

        // softmax over the 16 (l,p) slots of this head (16-lane aligned groups)
        const float lg = ol[(size_t)q * 384 + 256 + j];
        float m = lg;
#pragma unroll
        for (int o = 8; o; o >>= 1) m = fmaxf(m, __shfl_xor(m, o, 16));
        const float e = expf(lg - m);
        float sm = e;
#pragma unroll
        for (int o = 8; o; o >>= 1) sm += __shfl_xor(sm, o, 16);
        const float a = e / sm;

        const int p = lp * 8 + (h ^ (lp & 7));   // bijective bank-spread permutation
        float4 aw;
        aw.x = a * (wx0 * wy0);   // (y0,x0)
        aw.y = a * (wx0 * wy1);   // (y1,x0)
        aw.z = a * (wx1 * wy0);   // (y0,x1)
        aw.w = a * (wx1 * wy1);   // (y1,x1)
        int4 of;
        of.x = (st + y0i * ww + x0i) << 10;      // row byte offset (256 floats)
        of.y = (st + y1i * ww + x0i) << 10;
        of.z = (st + y0i * ww + x1i) << 10;
        of.w = (st + y1i * ww + x1i) << 10;
        s_aw[w][p] = aw;
        s_of[w][p] = of;
    }
    __syncthreads();

    const int h = lane >> 3;
    const char* vb = (const char*)value + (size_t)n * LEN_IN * C_DIM * 4 + (size_t)(lane * 16);
    float4 acc;
    acc.x = 0.f; acc.y = 0.f; acc.z = 0.f; acc.w = 0.f;
#pragma unroll
    for (int lp = 0; lp < 16; ++lp) {
        const int p = lp * 8 + (h ^ (lp & 7));
        const float4 aw = s_aw[w][p];
        const int4 of = s_of[w][p];
        const float4 v0 = *(const float4*)(vb + of.x);
        const float4 v1 = *(const float4*)(vb + of.y);
        const float4 v2 = *(const float4*)(vb + of.z);
        const float4 v3 = *(const float4*)(vb + of.w);
        acc.x += aw.x * v0.x + aw.y * v1.x + aw.z * v2.x + aw.w * v3.x;
        acc.y += aw.x * v0.y + aw.y * v1.y + aw.z * v2.y + aw.w * v3.y;
        acc.z += aw.x * v0.z + aw.y * v1.z + aw.z * v2.z + aw.w * v3.z;
        acc.w += aw.x * v0.w + aw.y * v1.w + aw.z * v2.w + aw.w * v3.w;
    }
    *(float4*)&tmp[(size_t)q * 256 + (size_t)(lane * 4)] = acc;
}

extern "C" void kernel_launch(void* const* d_in, const int* in_sizes, int n_in,
                              void* d_out, int out_size, void* d_ws, size_t ws_size,
                              hipStream_t stream) {
    const float* query         = (const float*)d_in[0];
    const float* refpts        = (const float*)d_in[1];
    const float* input_flatten = (const float*)d_in[2];
    // d_in[3] = input_spatial_shapes, d_in[4] = input_level_start_index (static, hardcoded)
    const float* w_off  = (const float*)d_in[5];
    const float* b_off  = (const float*)d_in[6];
    const float* w_attn = (const float*)d_in[7];
    const float* b_attn = (const float*)d_in[8];
    const float* w_val  = (const float*)d_in[9];
    const float* b_val  = (const float*)d_in[10];
    const float* w_out  = (const float*)d_in[11];
    const float* b_out  = (const float*)d_in[12];
    float* out = (float*)d_out;

    const size_t nr = (size_t)M_ROWS;            // 21760
    float* p = (float*)d_ws;
    float* value_ws = p; p += nr * 256;          // fp32 [M,256]
    float* ol_ws    = p; p += nr * 384;          // fp32 [M,384] = [offv | logits]
    float* tmp_ws   = p; p += nr * 256;          // fp32 [M,256]
    float* bc_ws    = p; p += 384;               // concat bias [b_off | b_attn]
    __half* wv_hi = (__half*)p;                  // weights hi/lo, transposed [NC][256]
    __half* wv_lo = wv_hi + 256 * 256;
    __half* wc_hi = wv_lo + 256 * 256;           // combined [384][256]
    __half* wc_lo = wc_hi + 384 * 256;
    __half* wt_hi = wc_lo + 384 * 256;
    __half* wt_lo = wt_hi + 256 * 256;

    convert_wt<<<256, 256, 0, stream>>>(w_val, wv_hi, wv_lo, 256);
    convert_wt<<<256, 256, 0, stream>>>(w_off, wc_hi, wc_lo, 256);
    convert_wt<<<128, 256, 0, stream>>>(w_attn, wc_hi + 256 * 256, wc_lo + 256 * 256, 128);
    convert_wt<<<256, 256, 0, stream>>>(w_out, wt_hi, wt_lo, 256);
    hipMemcpyAsync(bc_ws, b_off, 256 * sizeof(float), hipMemcpyDeviceToDevice, stream);
    hipMemcpyAsync(bc_ws + 256, b_attn, 128 * sizeof(float), hipMemcpyDeviceToDevice, stream);

    dim3 g256(2, M_ROWS / 128);   // (2, 170)
    dim3 g384(3, M_ROWS / 128);   // (3, 170)

    gemm_f16x3<256><<<g256, 256, 0, stream>>>(input_flatten, wv_hi, wv_lo, b_val, value_ws);
    gemm_f16x3<384><<<g384, 256, 0, stream>>>(query, wc_hi, wc_lo, bc_ws, ol_ws);

    sample_kernel<<<M_ROWS / 2, 128, 0, stream>>>(value_ws, ol_ws, refpts, tmp_ws);

    gemm_f16x3<256><<<g256, 256, 0, stream>>>(tmp_ws, wt_hi, wt_lo, b_out, out);
}

// Round 6
// 142.251 us; speedup vs baseline: 1.7581x; 1.0879x over previous
//
#include <hip/hip_runtime.h>
#include <hip/hip_fp16.h>
#include <math.h>

#define C_DIM 256
#define H_DIM 8
#define L_DIM 4
#define P_DIM 4
#define LQ 5440
#define LEN_IN 5440
#define NB 4
#define M_ROWS (NB * LQ)   // 21760

typedef __attribute__((ext_vector_type(8))) _Float16 f16x8;
typedef __attribute__((ext_vector_type(8))) unsigned short u16x8;
typedef __attribute__((ext_vector_type(4))) float f32x4;

__device__ __forceinline__ void split_f32(float a, __half& h, __half& l) {
    h = __float2half(a);
    l = __float2half(a - __half2float(h));
}

// ---- all weight splits + bias concat in ONE kernel (fewer launches) ----
// blocks 0..255: w_val -> wv ; 256..511: w_off -> wc ; 512..639: w_attn -> wc+256 ;
// 640..895: w_out -> wt ; 896: b_off -> bc ; 897: b_attn -> bc+256
__global__ __launch_bounds__(256) void convert_all(const float* __restrict__ w_val,
                                                   const float* __restrict__ w_off,
                                                   const float* __restrict__ w_attn,
                                                   const float* __restrict__ w_out,
                                                   const float* __restrict__ b_off,
                                                   const float* __restrict__ b_attn,
                                                   __half* __restrict__ wv_hi, __half* __restrict__ wv_lo,
                                                   __half* __restrict__ wc_hi, __half* __restrict__ wc_lo,
                                                   __half* __restrict__ wt_hi, __half* __restrict__ wt_lo,
                                                   float* __restrict__ bc) {
    const int b = blockIdx.x, k = threadIdx.x;
    if (b < 896) {
        const float* w; __half *hi, *lo; int ncols, col, orow;
        if (b < 256)      { w = w_val;  hi = wv_hi; lo = wv_lo; ncols = 256; col = b;       orow = col; }
        else if (b < 512) { w = w_off;  hi = wc_hi; lo = wc_lo; ncols = 256; col = b - 256; orow = col; }
        else if (b < 640) { w = w_attn; hi = wc_hi; lo = wc_lo; ncols = 128; col = b - 512; orow = col + 256; }
        else              { w = w_out;  hi = wt_hi; lo = wt_lo; ncols = 256; col = b - 640; orow = col; }
        const float a = w[(size_t)k * ncols + col];
        __half h, l;
        split_f32(a, h, l);
        hi[(size_t)orow * 256 + k] = h;
        lo[(size_t)orow * 256 + k] = l;
    } else if (b == 896) {
        bc[k] = b_off[k];
    } else {
        if (k < 128) bc[256 + k] = b_attn[k];
    }
}

// ---------------- f16x3 MFMA GEMM: out[M x NC] = A[M x 256] @ W^T + bias ------------
// A is fp32 [M][256]; hi/lo split happens INLINE during LDS staging (v_cvt).
// W pre-split hi/lo f16, TRANSPOSED [NC][256]. BM=128, BN template (64 or 128),
// BK=32, 256 threads = 2x2 waves; wave owns 64 x BN/2 (4 x BN/32 frags of 16x16x32).
// fp32 emulated as Ahi*Bhi + Alo*Bhi + Ahi*Blo (3 MFMA).
// LDS [comp][row][32] halfs, XOR chunk swizzle ch^((row>>1)&3) on 16B chunks.
// BN=64 -> 680 blocks, bounds(256,3): all blocks co-resident (fixes CU imbalance).
template <int NC, int BN, int MINW>
__global__ __launch_bounds__(256, MINW) void gemm_f16x3(const float* __restrict__ A,
                                                        const __half* __restrict__ Bhi,
                                                        const __half* __restrict__ Blo,
                                                        const float* __restrict__ bias,
                                                        float* __restrict__ outp) {
    constexpr int NF = BN / 32;      // B frags per wave
    constexpr int BCH = BN / 64;     // B chunks per thread per comp

    __shared__ __align__(16) __half sA[2][128][32];
    __shared__ __align__(16) __half sB[2][BN][32];

    const int n0 = blockIdx.x * BN;
    const int row0 = blockIdx.y * 128;
    const int t = threadIdx.x;
    const int w = t >> 6, lane = t & 63;
    const int bm = (w >> 1) * 64, bn = (w & 1) * (BN / 2);
    const int fr = lane & 15;   // frag row (A) / col (B) / col (C)
    const int fc = lane >> 4;   // frag k-chunk (0..3); C row group

    // A: 512 8-float chunks per tile; thread t handles chunks t, t+256
    const int ar1 = t >> 2, ar2 = ar1 + 64;
    const int ak8 = t & 3;
    const int asw1 = (ak8 ^ ((ar1 >> 1) & 3)) * 8;
    const int asw2 = (ak8 ^ ((ar2 >> 1) & 3)) * 8;
    // B: BN*4 16B chunks per comp
    const int bc8 = t & 3;
    int brr[BCH], bsw[BCH];
#pragma unroll
    for (int c = 0; c < BCH; ++c) {
        brr[c] = (t >> 2) + 64 * c;
        bsw[c] = (bc8 ^ ((brr[c] >> 1) & 3)) * 8;
    }

    const size_t ga1 = (size_t)(row0 + ar1) * 256 + ak8 * 8;   // fp32 floats
    const size_t ga2 = (size_t)(row0 + ar2) * 256 + ak8 * 8;
    size_t gb[BCH];
#pragma unroll
    for (int c = 0; c < BCH; ++c) gb[c] = (size_t)(n0 + brr[c]) * 256 + bc8 * 8;

    f32x4 acc[4][NF];
#pragma unroll
    for (int m = 0; m < 4; ++m)
#pragma unroll
        for (int n = 0; n < NF; ++n)
#pragma unroll
            for (int r = 0; r < 4; ++r) acc[m][n][r] = 0.f;

    float4 pa[4];
    float4 pb[2 * BCH];
    pa[0] = *(const float4*)(A + ga1);
    pa[1] = *(const float4*)(A + ga1 + 4);
    pa[2] = *(const float4*)(A + ga2);
    pa[3] = *(const float4*)(A + ga2 + 4);
#pragma unroll
    for (int c = 0; c < BCH; ++c) {
        pb[c] = *(const float4*)(Bhi + gb[c]);
        pb[BCH + c] = *(const float4*)(Blo + gb[c]);
    }

    for (int kt = 0; kt < 8; ++kt) {
        if (kt) __syncthreads();
        // inline split of the two A chunks
#pragma unroll
        for (int ch = 0; ch < 2; ++ch) {
            const float4 u = pa[2 * ch], v = pa[2 * ch + 1];
            const float e[8] = {u.x, u.y, u.z, u.w, v.x, v.y, v.z, v.w};
            u16x8 Hh, Ll;
#pragma unroll
            for (int i = 0; i < 8; ++i) {
                __half h, l;
                split_f32(e[i], h, l);
                Hh[i] = __half_as_ushort(h);
                Ll[i] = __half_as_ushort(l);
            }
            const int row = ch ? ar2 : ar1;
            const int sw = ch ? asw2 : asw1;
            *(u16x8*)&sA[0][row][sw] = Hh;
            *(u16x8*)&sA[1][row][sw] = Ll;
        }
#pragma unroll
        for (int c = 0; c < BCH; ++c) {
            *(float4*)&sB[0][brr[c]][bsw[c]] = pb[c];
            *(float4*)&sB[1][brr[c]][bsw[c]] = pb[BCH + c];
        }
        __syncthreads();
        if (kt < 7) {
            const size_t ko = (size_t)(kt + 1) * 32;
            pa[0] = *(const float4*)(A + ga1 + ko);
            pa[1] = *(const float4*)(A + ga1 + ko + 4);
            pa[2] = *(const float4*)(A + ga2 + ko);
            pa[3] = *(const float4*)(A + ga2 + ko + 4);
#pragma unroll
            for (int c = 0; c < BCH; ++c) {
                pb[c] = *(const float4*)(Bhi + gb[c] + ko);
                pb[BCH + c] = *(const float4*)(Blo + gb[c] + ko);
            }
        }

        f16x8 bhf[NF], blf[NF];
#pragma unroll
        for (int n = 0; n < NF; ++n) {
            const int rowb = bn + n * 16 + fr;
            const int swb = (fc ^ ((rowb >> 1) & 3)) * 8;
            bhf[n] = *(const f16x8*)&sB[0][rowb][swb];
            blf[n] = *(const f16x8*)&sB[1][rowb][swb];
        }
#pragma unroll
        for (int m = 0; m < 4; ++m) {
            const int rowa = bm + m * 16 + fr;
            const int swa = (fc ^ ((rowa >> 1) & 3)) * 8;
            const f16x8 ah = *(const f16x8*)&sA[0][rowa][swa];
            const f16x8 al = *(const f16x8*)&sA[1][rowa][swa];
#pragma unroll
            for (int n = 0; n < NF; ++n) {
                acc[m][n] = __builtin_amdgcn_mfma_f32_16x16x32_f16(ah, bhf[n], acc[m][n], 0, 0, 0);
                acc[m][n] = __builtin_amdgcn_mfma_f32_16x16x32_f16(al, bhf[n], acc[m][n], 0, 0, 0);
                acc[m][n] = __builtin_amdgcn_mfma_f32_16x16x32_f16(ah, blf[n], acc[m][n], 0, 0, 0);
            }
        }
    }

    // epilogue: C/D layout col = lane&15, row = (lane>>4)*4 + reg
#pragma unroll
    for (int n = 0; n < NF; ++n) {
        const int col = n0 + bn + n * 16 + fr;
        const float bv = bias[col];
#pragma unroll
        for (int m = 0; m < 4; ++m) {
            const int row = row0 + bm + m * 16 + fc * 4;
#pragma unroll
            for (int r = 0; r < 4; ++r)
                outp[(size_t)(row + r) * NC + col] = acc[m][n][r] + bv;
        }
    }
}

// ---------------- Sampling: softmax + bilinear gather + weighted sum ----------------
// 256 threads = 4 waves; each wave processes 2 queries SEQUENTIALLY with its private
// LDS slice -- NO __syncthreads anywhere (same-wave LDS ordering via lgkmcnt), so
// waves are fully independent and the SPI can stack 8 blocks/CU (32 waves).
// Gather addresses: wave-uniform base + 32-bit unsigned byte offset (saddr form,
// kills the per-address 64-bit add pair). LDS slot permutation p = lp*8+(h^(lp&7)):
// bijective, conflict-free for writers and readers.
__global__ __launch_bounds__(256) void sample_kernel(const float* __restrict__ value,   // [N*LEN_IN, C]
                                                     const float* __restrict__ ol,      // [N*LQ, 384]
                                                     const float* __restrict__ refpts,  // [N, LQ, L, 2]
                                                     float* __restrict__ tmp) {         // [N*LQ, C]
    const int t = threadIdx.x;
    const int w = t >> 6, lane = t & 63;

    __shared__ __align__(16) float4 s_aw[4][128];
    __shared__ __align__(16) uint4 s_of[4][128];

    const int h = lane >> 3;
    const unsigned l16 = (unsigned)(lane * 16);

    for (int it = 0; it < 2; ++it) {
        const int q = blockIdx.x * 8 + w * 2 + it;
        const int n = q / LQ;

#pragma unroll
        for (int s = 0; s < 2; ++s) {
            const int j = lane + 64 * s;     // slot = hq*16 + lp, lp = (l<<2)|p
            const int hq = j >> 4, lp = j & 15;
            const int l = lp >> 2;
            const int ww = 64 >> l;
            int st = 0;
            if (l == 1) st = 4096;
            else if (l == 2) st = 5120;
            else if (l == 3) st = 5376;

            const float2 oxy = *(const float2*)&ol[(size_t)q * 384 + 2 * j];
            const float2 rxy = *(const float2*)&refpts[((size_t)q * L_DIM + l) * 2];

            const float fw = (float)ww;
            const float x = fminf(fmaxf(rxy.x + oxy.x, 0.f), 1.f) * fw - 0.5f;
            const float y = fminf(fmaxf(rxy.y + oxy.y, 0.f), 1.f) * fw - 0.5f;
            const int xi = (int)floorf(x);
            const int yi = (int)floorf(y);
            const int x0i = min(max(xi, 0), ww - 1);
            const int x1i = min(max(xi + 1, 0), ww - 1);
            const int y0i = min(max(yi, 0), ww - 1);
            const int y1i = min(max(yi + 1, 0), ww - 1);
            const float wx0 = (float)x1i - x, wx1 = x - (float)x0i;
            const float wy0 = (float)y1i - y, wy1 = y - (float)y0i;

            // softmax over the 16 (l,p) slots of this head (16-lane aligned groups)
            const float lg = ol[(size_t)q * 384 + 256 + j];
            float m = lg;
#pragma unroll
            for (int o = 8; o; o >>= 1) m = fmaxf(m, __shfl_xor(m, o, 16));
            const float e = expf(lg - m);
            float sm = e;
#pragma unroll
            for (int o = 8; o; o >>= 1) sm += __shfl_xor(sm, o, 16);
            const float a = e / sm;

            const int p = lp * 8 + (hq ^ (lp & 7));   // bijective bank-spread permutation
            float4 aw;
            aw.x = a * (wx0 * wy0);   // (y0,x0)
            aw.y = a * (wx0 * wy1);   // (y1,x0)
            aw.z = a * (wx1 * wy0);   // (y0,x1)
            aw.w = a * (wx1 * wy1);   // (y1,x1)
            uint4 of;
            of.x = (unsigned)(st + y0i * ww + x0i) << 10;   // row byte offset
            of.y = (unsigned)(st + y1i * ww + x0i) << 10;
            of.z = (unsigned)(st + y0i * ww + x1i) << 10;
            of.w = (unsigned)(st + y1i * ww + x1i) << 10;
            s_aw[w][p] = aw;
            s_of[w][p] = of;
        }
        // no barrier: same-wave LDS write->read ordered by lgkmcnt

        const char* vbn = (const char*)value + (size_t)n * (LEN_IN * C_DIM * 4);  // wave-uniform
        float4 acc;
        acc.x = 0.f; acc.y = 0.f; acc.z = 0.f; acc.w = 0.f;
#pragma unroll
        for (int lp = 0; lp < 16; ++lp) {
            const int p = lp * 8 + (h ^ (lp & 7));
            const float4 aw = s_aw[w][p];
            const uint4 of = s_of[w][p];
            const float4 v0 = *(const float4*)(vbn + (of.x + l16));
            const float4 v1 = *(const float4*)(vbn + (of.y + l16));
            const float4 v2 = *(const float4*)(vbn + (of.z + l16));
            const float4 v3 = *(const float4*)(vbn + (of.w + l16));
            acc.x += aw.x * v0.x + aw.y * v1.x + aw.z * v2.x + aw.w * v3.x;
            acc.y += aw.x * v0.y + aw.y * v1.y + aw.z * v2.y + aw.w * v3.y;
            acc.z += aw.x * v0.z + aw.y * v1.z + aw.z * v2.z + aw.w * v3.z;
            acc.w += aw.x * v0.w + aw.y * v1.w + aw.z * v2.w + aw.w * v3.w;
        }
        *(float4*)&tmp[(size_t)q * 256 + (size_t)(lane * 4)] = acc;
    }
}

extern "C" void kernel_launch(void* const* d_in, const int* in_sizes, int n_in,
                              void* d_out, int out_size, void* d_ws, size_t ws_size,
                              hipStream_t stream) {
    const float* query         = (const float*)d_in[0];
    const float* refpts        = (const float*)d_in[1];
    const float* input_flatten = (const float*)d_in[2];
    // d_in[3] = input_spatial_shapes, d_in[4] = input_level_start_index (static, hardcoded)
    const float* w_off  = (const float*)d_in[5];
    const float* b_off  = (const float*)d_in[6];
    const float* w_attn = (const float*)d_in[7];
    const float* b_attn = (const float*)d_in[8];
    const float* w_val  = (const float*)d_in[9];
    const float* b_val  = (const float*)d_in[10];
    const float* w_out  = (const float*)d_in[11];
    const float* b_out  = (const float*)d_in[12];
    float* out = (float*)d_out;

    const size_t nr = (size_t)M_ROWS;            // 21760
    float* p = (float*)d_ws;
    float* value_ws = p; p += nr * 256;          // fp32 [M,256]
    float* ol_ws    = p; p += nr * 384;          // fp32 [M,384] = [offv | logits]
    float* tmp_ws   = p; p += nr * 256;          // fp32 [M,256]
    float* bc_ws    = p; p += 384;               // concat bias [b_off | b_attn]
    __half* wv_hi = (__half*)p;                  // weights hi/lo, transposed [NC][256]
    __half* wv_lo = wv_hi + 256 * 256;
    __half* wc_hi = wv_lo + 256 * 256;           // combined [384][256]
    __half* wc_lo = wc_hi + 384 * 256;
    __half* wt_hi = wc_lo + 384 * 256;
    __half* wt_lo = wt_hi + 256 * 256;

    convert_all<<<898, 256, 0, stream>>>(w_val, w_off, w_attn, w_out, b_off, b_attn,
                                         wv_hi, wv_lo, wc_hi, wc_lo, wt_hi, wt_lo, bc_ws);

    dim3 g256(4, M_ROWS / 128);   // (4, 170) = 680 blocks, BN=64
    dim3 g384(3, M_ROWS / 128);   // (3, 170) = 510 blocks, BN=128

    gemm_f16x3<256, 64, 3><<<g256, 256, 0, stream>>>(input_flatten, wv_hi, wv_lo, b_val, value_ws);
    gemm_f16x3<384, 128, 2><<<g384, 256, 0, stream>>>(query, wc_hi, wc_lo, bc_ws, ol_ws);

    sample_kernel<<<M_ROWS / 8, 256, 0, stream>>>(value_ws, ol_ws, refpts, tmp_ws);

    gemm_f16x3<256, 64, 3><<<g256, 256, 0, stream>>>(tmp_ws, wt_hi, wt_lo, b_out, out);
}

// Round 7
// 138.555 us; speedup vs baseline: 1.8050x; 1.0267x over previous
//
#include <hip/hip_runtime.h>
#include <hip/hip_fp16.h>
#include <math.h>

#define C_DIM 256
#define H_DIM 8
#define L_DIM 4
#define P_DIM 4
#define LQ 5440
#define LEN_IN 5440
#define NB 4
#define M_ROWS (NB * LQ)   // 21760

typedef __attribute__((ext_vector_type(8))) _Float16 f16x8;
typedef __attribute__((ext_vector_type(8))) unsigned short u16x8;
typedef __attribute__((ext_vector_type(4))) float f32x4;

__device__ __forceinline__ void split_f32(float a, __half& h, __half& l) {
    h = __float2half(a);
    l = __float2half(a - __half2float(h));
}

// ---- all weight splits + bias concat in ONE kernel (fewer launches) ----
// blocks 0..255: w_val -> wv ; 256..511: w_off -> wc ; 512..639: w_attn -> wc+256 ;
// 640..895: w_out -> wt ; 896: b_off -> bc ; 897: b_attn -> bc+256
__global__ __launch_bounds__(256) void convert_all(const float* __restrict__ w_val,
                                                   const float* __restrict__ w_off,
                                                   const float* __restrict__ w_attn,
                                                   const float* __restrict__ w_out,
                                                   const float* __restrict__ b_off,
                                                   const float* __restrict__ b_attn,
                                                   __half* __restrict__ wv_hi, __half* __restrict__ wv_lo,
                                                   __half* __restrict__ wc_hi, __half* __restrict__ wc_lo,
                                                   __half* __restrict__ wt_hi, __half* __restrict__ wt_lo,
                                                   float* __restrict__ bc) {
    const int b = blockIdx.x, k = threadIdx.x;
    if (b < 896) {
        const float* w; __half *hi, *lo; int ncols, col, orow;
        if (b < 256)      { w = w_val;  hi = wv_hi; lo = wv_lo; ncols = 256; col = b;       orow = col; }
        else if (b < 512) { w = w_off;  hi = wc_hi; lo = wc_lo; ncols = 256; col = b - 256; orow = col; }
        else if (b < 640) { w = w_attn; hi = wc_hi; lo = wc_lo; ncols = 128; col = b - 512; orow = col + 256; }
        else              { w = w_out;  hi = wt_hi; lo = wt_lo; ncols = 256; col = b - 640; orow = col; }
        const float a = w[(size_t)k * ncols + col];
        __half h, l;
        split_f32(a, h, l);
        hi[(size_t)orow * 256 + k] = h;
        lo[(size_t)orow * 256 + k] = l;
    } else if (b == 896) {
        bc[k] = b_off[k];
    } else {
        if (k < 128) bc[256 + k] = b_attn[k];
    }
}

// ---------------- f16x3 MFMA GEMM: out[M x NC] = A[M x 256] @ W^T + bias ------------
// A is fp32 [M][256]; hi/lo split happens INLINE during LDS staging (v_cvt).
// W pre-split hi/lo f16, TRANSPOSED [NC][256]. BM=128, BN template (64 or 128),
// BK=32, 256 threads = 2x2 waves; wave owns 64 x BN/2 (4 x BN/32 frags of 16x16x32).
// fp32 emulated as Ahi*Bhi + Alo*Bhi + Ahi*Blo (3 MFMA).
// LDS [comp][row][32] halfs, XOR chunk swizzle ch^((row>>1)&3) on 16B chunks.
// BN=64: 24KB LDS, MINW=4 -> 4 blocks/CU resident (more ds_read/MFMA overlap).
template <int NC, int BN, int MINW>
__global__ __launch_bounds__(256, MINW) void gemm_f16x3(const float* __restrict__ A,
                                                        const __half* __restrict__ Bhi,
                                                        const __half* __restrict__ Blo,
                                                        const float* __restrict__ bias,
                                                        float* __restrict__ outp) {
    constexpr int NF = BN / 32;      // B frags per wave
    constexpr int BCH = BN / 64;     // B chunks per thread per comp

    __shared__ __align__(16) __half sA[2][128][32];
    __shared__ __align__(16) __half sB[2][BN][32];

    const int n0 = blockIdx.x * BN;
    const int row0 = blockIdx.y * 128;
    const int t = threadIdx.x;
    const int w = t >> 6, lane = t & 63;
    const int bm = (w >> 1) * 64, bn = (w & 1) * (BN / 2);
    const int fr = lane & 15;   // frag row (A) / col (B) / col (C)
    const int fc = lane >> 4;   // frag k-chunk (0..3); C row group

    // A: 512 8-float chunks per tile; thread t handles chunks t, t+256
    const int ar1 = t >> 2, ar2 = ar1 + 64;
    const int ak8 = t & 3;
    const int asw1 = (ak8 ^ ((ar1 >> 1) & 3)) * 8;
    const int asw2 = (ak8 ^ ((ar2 >> 1) & 3)) * 8;
    // B: BN*4 16B chunks per comp
    const int bc8 = t & 3;
    int brr[BCH], bsw[BCH];
#pragma unroll
    for (int c = 0; c < BCH; ++c) {
        brr[c] = (t >> 2) + 64 * c;
        bsw[c] = (bc8 ^ ((brr[c] >> 1) & 3)) * 8;
    }

    const size_t ga1 = (size_t)(row0 + ar1) * 256 + ak8 * 8;   // fp32 floats
    const size_t ga2 = (size_t)(row0 + ar2) * 256 + ak8 * 8;
    size_t gb[BCH];
#pragma unroll
    for (int c = 0; c < BCH; ++c) gb[c] = (size_t)(n0 + brr[c]) * 256 + bc8 * 8;

    f32x4 acc[4][NF];
#pragma unroll
    for (int m = 0; m < 4; ++m)
#pragma unroll
        for (int n = 0; n < NF; ++n)
#pragma unroll
            for (int r = 0; r < 4; ++r) acc[m][n][r] = 0.f;

    float4 pa[4];
    float4 pb[2 * BCH];
    pa[0] = *(const float4*)(A + ga1);
    pa[1] = *(const float4*)(A + ga1 + 4);
    pa[2] = *(const float4*)(A + ga2);
    pa[3] = *(const float4*)(A + ga2 + 4);
#pragma unroll
    for (int c = 0; c < BCH; ++c) {
        pb[c] = *(const float4*)(Bhi + gb[c]);
        pb[BCH + c] = *(const float4*)(Blo + gb[c]);
    }

    for (int kt = 0; kt < 8; ++kt) {
        if (kt) __syncthreads();
        // inline split of the two A chunks
#pragma unroll
        for (int ch = 0; ch < 2; ++ch) {
            const float4 u = pa[2 * ch], v = pa[2 * ch + 1];
            const float e[8] = {u.x, u.y, u.z, u.w, v.x, v.y, v.z, v.w};
            u16x8 Hh, Ll;
#pragma unroll
            for (int i = 0; i < 8; ++i) {
                __half h, l;
                split_f32(e[i], h, l);
                Hh[i] = __half_as_ushort(h);
                Ll[i] = __half_as_ushort(l);
            }
            const int row = ch ? ar2 : ar1;
            const int sw = ch ? asw2 : asw1;
            *(u16x8*)&sA[0][row][sw] = Hh;
            *(u16x8*)&sA[1][row][sw] = Ll;
        }
#pragma unroll
        for (int c = 0; c < BCH; ++c) {
            *(float4*)&sB[0][brr[c]][bsw[c]] = pb[c];
            *(float4*)&sB[1][brr[c]][bsw[c]] = pb[BCH + c];
        }
        __syncthreads();
        if (kt < 7) {
            const size_t ko = (size_t)(kt + 1) * 32;
            pa[0] = *(const float4*)(A + ga1 + ko);
            pa[1] = *(const float4*)(A + ga1 + ko + 4);
            pa[2] = *(const float4*)(A + ga2 + ko);
            pa[3] = *(const float4*)(A + ga2 + ko + 4);
#pragma unroll
            for (int c = 0; c < BCH; ++c) {
                pb[c] = *(const float4*)(Bhi + gb[c] + ko);
                pb[BCH + c] = *(const float4*)(Blo + gb[c] + ko);
            }
        }

        f16x8 bhf[NF], blf[NF];
#pragma unroll
        for (int n = 0; n < NF; ++n) {
            const int rowb = bn + n * 16 + fr;
            const int swb = (fc ^ ((rowb >> 1) & 3)) * 8;
            bhf[n] = *(const f16x8*)&sB[0][rowb][swb];
            blf[n] = *(const f16x8*)&sB[1][rowb][swb];
        }
#pragma unroll
        for (int m = 0; m < 4; ++m) {
            const int rowa = bm + m * 16 + fr;
            const int swa = (fc ^ ((rowa >> 1) & 3)) * 8;
            const f16x8 ah = *(const f16x8*)&sA[0][rowa][swa];
            const f16x8 al = *(const f16x8*)&sA[1][rowa][swa];
#pragma unroll
            for (int n = 0; n < NF; ++n) {
                acc[m][n] = __builtin_amdgcn_mfma_f32_16x16x32_f16(ah, bhf[n], acc[m][n], 0, 0, 0);
                acc[m][n] = __builtin_amdgcn_mfma_f32_16x16x32_f16(al, bhf[n], acc[m][n], 0, 0, 0);
                acc[m][n] = __builtin_amdgcn_mfma_f32_16x16x32_f16(ah, blf[n], acc[m][n], 0, 0, 0);
            }
        }
    }

    // epilogue: C/D layout col = lane&15, row = (lane>>4)*4 + reg
#pragma unroll
    for (int n = 0; n < NF; ++n) {
        const int col = n0 + bn + n * 16 + fr;
        const float bv = bias[col];
#pragma unroll
        for (int m = 0; m < 4; ++m) {
            const int row = row0 + bm + m * 16 + fc * 4;
#pragma unroll
            for (int r = 0; r < 4; ++r)
                outp[(size_t)(row + r) * NC + col] = acc[m][n][r] + bv;
        }
    }
}

// ---------------- Sampling: softmax + bilinear gather + weighted sum ----------------
// 256 threads = 4 waves; each wave processes 2 queries sequentially, private LDS
// slice, no barrier. XCD BATCH AFFINITY: dispatch round-robins blocks over the 8
// XCDs (bid&7 ~ xcd), so XCD pair {2n,2n+1} is given only batch n's queries ->
// each XCD's value working set is one batch slice (5.6 MB ~ its 4 MiB L2) instead
// of all 22.3 MB. Gathers: wave-uniform base + 32-bit offsets, 128B coalesced.
// LDS slot permutation p = lp*8+(h^(lp&7)): conflict-free writers and readers.
__global__ __launch_bounds__(256) void sample_kernel(const float* __restrict__ value,   // [N*LEN_IN, C]
                                                     const float* __restrict__ ol,      // [N*LQ, 384]
                                                     const float* __restrict__ refpts,  // [N, LQ, L, 2]
                                                     float* __restrict__ tmp) {         // [N*LQ, C]
    const int t = threadIdx.x;
    const int w = t >> 6, lane = t & 63;

    __shared__ __align__(16) float4 s_aw[4][128];
    __shared__ __align__(16) uint4 s_of[4][128];

    const int h = lane >> 3;
    const unsigned l16 = (unsigned)(lane * 16);

    // XCD-affine block -> query mapping (bijective over [0, M_ROWS/8))
    const int bid = blockIdx.x;            // 0..2719
    const int xcd = bid & 7;
    const int pos = bid >> 3;              // 0..339
    const int nb = xcd >> 1;               // batch handled by this XCD pair
    const int qgrp = (xcd & 1) * 340 + pos;   // 0..679 within batch
    const int n = nb;

    const char* vbn = (const char*)value + (size_t)n * (LEN_IN * C_DIM * 4);  // wave-uniform

    for (int it = 0; it < 2; ++it) {
        const int q = n * LQ + qgrp * 8 + w * 2 + it;

#pragma unroll
        for (int s = 0; s < 2; ++s) {
            const int j = lane + 64 * s;     // slot = hq*16 + lp, lp = (l<<2)|p
            const int hq = j >> 4, lp = j & 15;
            const int l = lp >> 2;
            const int ww = 64 >> l;
            int st = 0;
            if (l == 1) st = 4096;
            else if (l == 2) st = 5120;
            else if (l == 3) st = 5376;

            const float2 oxy = *(const float2*)&ol[(size_t)q * 384 + 2 * j];
            const float2 rxy = *(const float2*)&refpts[((size_t)q * L_DIM + l) * 2];

            const float fw = (float)ww;
            const float x = fminf(fmaxf(rxy.x + oxy.x, 0.f), 1.f) * fw - 0.5f;
            const float y = fminf(fmaxf(rxy.y + oxy.y, 0.f), 1.f) * fw - 0.5f;
            const int xi = (int)floorf(x);
            const int yi = (int)floorf(y);
            const int x0i = min(max(xi, 0), ww - 1);
            const int x1i = min(max(xi + 1, 0), ww - 1);
            const int y0i = min(max(yi, 0), ww - 1);
            const int y1i = min(max(yi + 1, 0), ww - 1);
            const float wx0 = (float)x1i - x, wx1 = x - (float)x0i;
            const float wy0 = (float)y1i - y, wy1 = y - (float)y0i;

            // softmax over the 16 (l,p) slots of this head (16-lane aligned groups)
            const float lg = ol[(size_t)q * 384 + 256 + j];
            float m = lg;
#pragma unroll
            for (int o = 8; o; o >>= 1) m = fmaxf(m, __shfl_xor(m, o, 16));
            const float e = expf(lg - m);
            float sm = e;
#pragma unroll
            for (int o = 8; o; o >>= 1) sm += __shfl_xor(sm, o, 16);
            const float a = e / sm;

            const int p = lp * 8 + (hq ^ (lp & 7));   // bijective bank-spread permutation
            float4 aw;
            aw.x = a * (wx0 * wy0);   // (y0,x0)
            aw.y = a * (wx0 * wy1);   // (y1,x0)
            aw.z = a * (wx1 * wy0);   // (y0,x1)
            aw.w = a * (wx1 * wy1);   // (y1,x1)
            uint4 of;
            of.x = (unsigned)(st + y0i * ww + x0i) << 10;   // row byte offset
            of.y = (unsigned)(st + y1i * ww + x0i) << 10;
            of.z = (unsigned)(st + y0i * ww + x1i) << 10;
            of.w = (unsigned)(st + y1i * ww + x1i) << 10;
            s_aw[w][p] = aw;
            s_of[w][p] = of;
        }
        // no barrier: same-wave LDS write->read ordered by lgkmcnt

        float4 acc;
        acc.x = 0.f; acc.y = 0.f; acc.z = 0.f; acc.w = 0.f;
#pragma unroll
        for (int lp = 0; lp < 16; ++lp) {
            const int p = lp * 8 + (h ^ (lp & 7));
            const float4 aw = s_aw[w][p];
            const uint4 of = s_of[w][p];
            const float4 v0 = *(const float4*)(vbn + (of.x + l16));
            const float4 v1 = *(const float4*)(vbn + (of.y + l16));
            const float4 v2 = *(const float4*)(vbn + (of.z + l16));
            const float4 v3 = *(const float4*)(vbn + (of.w + l16));
            acc.x += aw.x * v0.x + aw.y * v1.x + aw.z * v2.x + aw.w * v3.x;
            acc.y += aw.x * v0.y + aw.y * v1.y + aw.z * v2.y + aw.w * v3.y;
            acc.z += aw.x * v0.z + aw.y * v1.z + aw.z * v2.z + aw.w * v3.z;
            acc.w += aw.x * v0.w + aw.y * v1.w + aw.z * v2.w + aw.w * v3.w;
        }
        *(float4*)&tmp[(size_t)q * 256 + (size_t)(lane * 4)] = acc;
    }
}

extern "C" void kernel_launch(void* const* d_in, const int* in_sizes, int n_in,
                              void* d_out, int out_size, void* d_ws, size_t ws_size,
                              hipStream_t stream) {
    const float* query         = (const float*)d_in[0];
    const float* refpts        = (const float*)d_in[1];
    const float* input_flatten = (const float*)d_in[2];
    // d_in[3] = input_spatial_shapes, d_in[4] = input_level_start_index (static, hardcoded)
    const float* w_off  = (const float*)d_in[5];
    const float* b_off  = (const float*)d_in[6];
    const float* w_attn = (const float*)d_in[7];
    const float* b_attn = (const float*)d_in[8];
    const float* w_val  = (const float*)d_in[9];
    const float* b_val  = (const float*)d_in[10];
    const float* w_out  = (const float*)d_in[11];
    const float* b_out  = (const float*)d_in[12];
    float* out = (float*)d_out;

    const size_t nr = (size_t)M_ROWS;            // 21760
    float* p = (float*)d_ws;
    float* value_ws = p; p += nr * 256;          // fp32 [M,256]
    float* ol_ws    = p; p += nr * 384;          // fp32 [M,384] = [offv | logits]
    float* tmp_ws   = p; p += nr * 256;          // fp32 [M,256]
    float* bc_ws    = p; p += 384;               // concat bias [b_off | b_attn]
    __half* wv_hi = (__half*)p;                  // weights hi/lo, transposed [NC][256]
    __half* wv_lo = wv_hi + 256 * 256;
    __half* wc_hi = wv_lo + 256 * 256;           // combined [384][256]
    __half* wc_lo = wc_hi + 384 * 256;
    __half* wt_hi = wc_lo + 384 * 256;
    __half* wt_lo = wt_hi + 256 * 256;

    convert_all<<<898, 256, 0, stream>>>(w_val, w_off, w_attn, w_out, b_off, b_attn,
                                         wv_hi, wv_lo, wc_hi, wc_lo, wt_hi, wt_lo, bc_ws);

    dim3 g256(4, M_ROWS / 128);   // (4, 170) = 680 blocks, BN=64
    dim3 g384(3, M_ROWS / 128);   // (3, 170) = 510 blocks, BN=128

    gemm_f16x3<256, 64, 4><<<g256, 256, 0, stream>>>(input_flatten, wv_hi, wv_lo, b_val, value_ws);
    gemm_f16x3<384, 128, 2><<<g384, 256, 0, stream>>>(query, wc_hi, wc_lo, bc_ws, ol_ws);

    sample_kernel<<<M_ROWS / 8, 256, 0, stream>>>(value_ws, ol_ws, refpts, tmp_ws);

    gemm_f16x3<256, 64, 4><<<g256, 256, 0, stream>>>(tmp_ws, wt_hi, wt_lo, b_out, out);
}